// Round 13
// baseline (55.790 us; speedup 1.0000x reference)
//
#include <hip/hip_runtime.h>
#include <math.h>

typedef _Float16 half8 __attribute__((ext_vector_type(8)));
typedef float f32x4 __attribute__((ext_vector_type(4)));

#define RLT (1.0f/0.07f)

// out layout (flat fp32):
//   A      [256,196]  @ 0
//   logits [256,258]  @ 50176
//   Pos    [256,196]  @ 116224
//   Neg    [256,196]  @ 166400
//   A0_ref [256,256]  @ 216576

// aud_pk layout: [c>>3][m][c&7] fp16 — 64 groups x 256 m x 8 halves (16B per (cg,m))
__global__ __launch_bounds__(256) void prep_aud_pk(const float* __restrict__ aud,
                                                   _Float16* __restrict__ aud_pk) {
    int m = blockIdx.x, t = threadIdx.x;
    float a0 = aud[m * 512 + t];
    float a1 = aud[m * 512 + 256 + t];
    float s = a0 * a0 + a1 * a1;
    #pragma unroll
    for (int off = 32; off; off >>= 1) s += __shfl_down(s, off, 64);
    __shared__ float wsum[4];
    __shared__ float rns;
    if ((t & 63) == 0) wsum[t >> 6] = s;
    __syncthreads();
    if (t == 0) rns = 1.0f / fmaxf(sqrtf(wsum[0] + wsum[1] + wsum[2] + wsum[3]), 1e-12f);
    __syncthreads();
    float rn = rns;
    int c0 = t, c1 = t + 256;
    aud_pk[(c0 >> 3) * 2048 + m * 8 + (c0 & 7)] = (_Float16)(a0 * rn);
    aud_pk[(c1 >> 3) * 2048 + m * 8 + (c1 & 7)] = (_Float16)(a1 * rn);
}

// ONE block per n (grid 256 = 1 block/CU, 8 waves, 256-VGPR budget).
// Wave w owns m-slice [32w, 32w+32): B-frags are wave-private -> global->reg
// from L2-resident aud_pk (NO B LDS, NO gll16). A is LDS-staged (shared) with
// 2-slot reg prefetch; its waits are register deps only. The barrier carries
// ONLY LDS semantics: lgkmcnt(0) + raw s_barrier — the A HBM stream and B L2
// stream are never drained by a barrier.
__global__ __launch_bounds__(512, 2) void av_breg(const float* __restrict__ img,
                                                  const _Float16* __restrict__ aud_pk,
                                                  float* __restrict__ out) {
    const int n = blockIdx.x;
    const int tid = threadIdx.x;
    const int w = tid >> 6, l = tid & 63;
    const int kk = l >> 4, lm = l & 15;

    __shared__ _Float16 __align__(16) Abuf[2][4][208][8];  // [buf][kg][row][j] 26.6 KB
    __shared__ float nrm_parts[2][196];
    __shared__ float rnorm_s[208];

    // zero the pad rows (196..207) of both A buffers once (never overwritten)
    if (tid < 96) {
        int b = tid / 48, rem = tid % 48, kg = rem / 12, row = 196 + rem % 12;
        *(float4*)&Abuf[b][kg][row][0] = make_float4(0.f, 0.f, 0.f, 0.f);
    }

    const float* imgn = img + (size_t)n * (512 * 196);
    const bool act = tid < 392;            // A staging: fixed hw row, 16 consecutive c
    const int p   = act ? tid / 196 : 0;   // c half within the 32-c step
    const int hwl = act ? tid % 196 : 0;   // row
    float nrm = 0.f;
    float av0[16], av1[16];
    half8 b0[2], b1[2];

    // per-lane B base (halves): aud_pk[(4t+kk)*2048 + (32w + mt*16 + lm)*8]
    const _Float16* bbase = aud_pk + (size_t)kk * 2048 + (32 * w + lm) * 8;

    #define LOAD_B(dst, t)                                                          \
        do {                                                                        \
            const _Float16* bp = bbase + (size_t)(t) * 8192;                        \
            dst[0] = *(const half8*)(bp);                                           \
            dst[1] = *(const half8*)(bp + 128);                                     \
        } while (0)

    #define LOAD_A_TO(dst, t)                                                       \
        do {                                                                        \
            if (act) {                                                              \
                const float* src = imgn + ((size_t)(32 * (t) + p * 16)) * 196 + hwl;\
                _Pragma("unroll")                                                   \
                for (int i = 0; i < 16; i++) dst[i] = src[i * 196];                 \
            }                                                                       \
        } while (0)

    #define STAGE_A_FROM(srcv, buf)                                                 \
        do {                                                                        \
            if (act) {                                                              \
                half8 h0, h1;                                                       \
                _Pragma("unroll")                                                   \
                for (int i = 0; i < 8; i++) {                                       \
                    h0[i] = (_Float16)srcv[i];                                      \
                    h1[i] = (_Float16)srcv[8 + i];                                  \
                    nrm += srcv[i] * srcv[i] + srcv[8 + i] * srcv[8 + i];           \
                }                                                                   \
                *(half8*)&Abuf[buf][2 * p][hwl][0]     = h0;                        \
                *(half8*)&Abuf[buf][2 * p + 1][hwl][0] = h1;                        \
            }                                                                       \
        } while (0)

    // ---- prologue: A(0)->av0 -> stage buf0; B(0)->b0; A(1)->av1 in flight
    LOAD_A_TO(av0, 0);
    LOAD_B(b0, 0);
    STAGE_A_FROM(av0, 0);
    LOAD_A_TO(av1, 1);
    asm volatile("s_waitcnt lgkmcnt(0)" ::: "memory");
    __builtin_amdgcn_s_barrier();
    __builtin_amdgcn_sched_barrier(0);

    f32x4 acc[13][2];
    #pragma unroll
    for (int ht = 0; ht < 13; ht++) {
        acc[ht][0] = (f32x4){0.f, 0.f, 0.f, 0.f};
        acc[ht][1] = (f32x4){0.f, 0.f, 0.f, 0.f};
    }

    // A-frag base (halves): Abuf[buf][kk][ht*16+lm][0] ; + ht*128
    const int aoff = kk * 1664 + lm * 8;

    // step t: [issue B(t+1)] [issue A(t+2)] [13x {ds_read afrag; 2 MFMA} from cur]
    //         [cvt+ds_write A(t+1)] [lgkm0; s_barrier]  (no vmem at barrier!)
    #define STEP(t, cur, bcur, bnxt, loadSlot, stageSlot)                           \
        do {                                                                        \
            const int nb_ = (cur) ^ 1;                                              \
            if ((t) <= 14) LOAD_B(bnxt, (t) + 1);                                   \
            if ((t) <= 13) LOAD_A_TO(loadSlot, (t) + 2);                            \
            {                                                                       \
                const _Float16* Ab = &Abuf[cur][0][0][0];                           \
                __builtin_amdgcn_s_setprio(1);                                      \
                _Pragma("unroll")                                                   \
                for (int ht = 0; ht < 13; ht++) {                                   \
                    half8 af = *(const half8*)(Ab + aoff + ht * 128);               \
                    acc[ht][0] = __builtin_amdgcn_mfma_f32_16x16x32_f16(            \
                        af, bcur[0], acc[ht][0], 0, 0, 0);                          \
                    acc[ht][1] = __builtin_amdgcn_mfma_f32_16x16x32_f16(            \
                        af, bcur[1], acc[ht][1], 0, 0, 0);                          \
                }                                                                   \
                __builtin_amdgcn_s_setprio(0);                                      \
            }                                                                       \
            __builtin_amdgcn_sched_barrier(0);                                      \
            if ((t) <= 14) STAGE_A_FROM(stageSlot, nb_);                            \
            if ((t) < 15) {                                                         \
                asm volatile("s_waitcnt lgkmcnt(0)" ::: "memory");                  \
                __builtin_amdgcn_s_barrier();                                       \
                __builtin_amdgcn_sched_barrier(0);                                  \
            }                                                                       \
        } while (0)

    #pragma unroll
    for (int tt = 0; tt < 16; tt += 2) {
        STEP(tt,     0, b0, b1, av0, av1);   // use B(t), load B(t+1); load A(t+2)->av0, stage A(t+1) from av1
        STEP(tt + 1, 1, b1, b0, av1, av0);
    }

    #undef STEP
    #undef LOAD_B
    #undef LOAD_A_TO
    #undef STAGE_A_FROM

    // ---- img row norms (each row fully covered: 2 p x 16 c x 16 steps = 512 c)
    if (act) nrm_parts[p][hwl] = nrm;
    __syncthreads();
    if (tid < 208) {
        float v = 0.f;
        if (tid < 196)
            v = 1.0f / fmaxf(sqrtf(nrm_parts[0][tid] + nrm_parts[1][tid]), 1e-12f);
        rnorm_s[tid] = v;
    }
    __syncthreads();

    // ---- per-wave fused epilogue: wave w owns m in [32w, 32w+32), all hw rows.
    // C/D: hw = ht*16 + kk*4 + r, m = 32w + mt*16 + lm.
    float mx[2], sw[2], swa[2];
    #pragma unroll
    for (int mt = 0; mt < 2; mt++) { mx[mt] = -1e30f; sw[mt] = 0.f; swa[mt] = 0.f; }
    float s1n = 0.f, s1d = 0.f, s2n = 0.f, s2d = 0.f;
    const int dw = n >> 5, dmt = (n >> 4) & 1, dlm = n & 15;
    const bool isdiag = (w == dw) && (lm == dlm);

    #pragma unroll
    for (int ht = 0; ht < 13; ht++) {
        int rowb = ht * 16 + (kk << 2);
        #pragma unroll
        for (int r = 0; r < 4; r++) {
            int hw = rowb + r;
            float rn = rnorm_s[hw];
            bool valid = hw < 196;
            #pragma unroll
            for (int mt = 0; mt < 2; mt++) {
                float a0 = acc[ht][mt][r] * rn;
                if (valid) {
                    float wg = 1.0f / (1.0f + __expf((0.65f - a0) * (1.0f / 0.03f)));
                    mx[mt]  = fmaxf(mx[mt], a0);
                    sw[mt] += wg;
                    swa[mt] += wg * a0;
                    if (isdiag && mt == dmt) {
                        out[n * 196 + hw] = a0;                 // A
                        out[116224 + n * 196 + hw] = wg;        // Pos
                        float p2 = 1.0f / (1.0f + __expf((0.40f - a0) * (1.0f / 0.03f)));
                        float ng = 1.0f - p2;
                        out[166400 + n * 196 + hw] = ng;        // Neg
                        s1n += wg * a0; s1d += wg;
                        s2n += ng * a0; s2d += ng;
                    }
                }
            }
        }
    }

    // reduce over kk (lanes 16 apart share m)
    #pragma unroll
    for (int mt = 0; mt < 2; mt++) {
        float m1 = mx[mt], v1 = sw[mt], v2 = swa[mt];
        m1 = fmaxf(m1, __shfl_xor(m1, 16, 64)); v1 += __shfl_xor(v1, 16, 64); v2 += __shfl_xor(v2, 16, 64);
        m1 = fmaxf(m1, __shfl_xor(m1, 32, 64)); v1 += __shfl_xor(v1, 32, 64); v2 += __shfl_xor(v2, 32, 64);
        if (l < 16) {
            int m = w * 32 + mt * 16 + l;
            float sim = v2 / v1;
            if (m == n) sim *= -99.0f;
            out[50176 + n * 258 + 1 + m] = sim * RLT;
            out[216576 + n * 256 + m] = m1;
        }
    }
    // diag logits (sim1, sim2)
    {
        float a = s1n, b = s1d, c = s2n, d = s2d;
        a += __shfl_xor(a, 16, 64); b += __shfl_xor(b, 16, 64);
        c += __shfl_xor(c, 16, 64); d += __shfl_xor(d, 16, 64);
        a += __shfl_xor(a, 32, 64); b += __shfl_xor(b, 32, 64);
        c += __shfl_xor(c, 32, 64); d += __shfl_xor(d, 32, 64);
        if (isdiag && l < 16) {
            out[50176 + n * 258]       = (a / b) * RLT;
            out[50176 + n * 258 + 257] = (c / d) * RLT;
        }
    }
}

extern "C" void kernel_launch(void* const* d_in, const int* in_sizes, int n_in,
                              void* d_out, int out_size, void* d_ws, size_t ws_size,
                              hipStream_t stream) {
    const float* img = (const float*)d_in[0];
    const float* aud = (const float*)d_in[1];
    float* out = (float*)d_out;
    _Float16* aud_pk = (_Float16*)d_ws;   // 512*256 fp16 = 256 KB

    prep_aud_pk<<<256, 256, 0, stream>>>(aud, aud_pk);
    av_breg<<<256, 512, 0, stream>>>(img, aud_pk, out);
}